// Round 15
// baseline (34.641 us; speedup 1.0000x reference)
//
#include <hip/hip_runtime.h>
#include <hip/hip_bf16.h>

#define BDIM 4096
#define DDIM 512
#define BT 256                    // block tile (rows == cols)
#define BK 32                     // K per tile-step
#define NKT (DDIM / BK)           // 16 K tiles
#define NPAN (BDIM / BT)          // 16 panels
#define GRIDX (NPAN * NPAN)       // 256 blocks = 1 per CU

typedef __bf16 bf16x8 __attribute__((ext_vector_type(8)));
typedef float f32x4 __attribute__((ext_vector_type(4)));
typedef unsigned short ushort_t;

#define WAITV4() asm volatile("s_waitcnt vmcnt(4)" ::: "memory")
#define WAITV0() asm volatile("s_waitcnt vmcnt(0)" ::: "memory")
#define BAR()    asm volatile("s_barrier" ::: "memory")

__device__ inline ushort_t f2bf(float f) {
  __hip_bfloat16 h = __float2bfloat16(f);
  return *reinterpret_cast<ushort_t*>(&h);
}

// order-preserving float <-> uint mapping (monotonic) for atomic min/max
__device__ inline unsigned int enc_f32(float x) {
  unsigned int u = __float_as_uint(x);
  return (u & 0x80000000u) ? ~u : (u | 0x80000000u);
}
__device__ inline float dec_f32(unsigned int e) {
  unsigned int u = (e & 0x80000000u) ? (e ^ 0x80000000u) : ~e;
  return __uint_as_float(u);
}

// ---------------- kernel 1: L2-normalize rows, emit bf16; init atomics -----
__global__ __launch_bounds__(256) void norm_kernel(const float* __restrict__ x,
                                                   ushort_t* __restrict__ e,
                                                   unsigned int* __restrict__ minpos_e,
                                                   unsigned int* __restrict__ maxneg_e) {
  if (blockIdx.x == 0) {  // init atomic arrays (stream order: before gemm)
    const unsigned int init_min = enc_f32(1e30f);
    const unsigned int init_max = enc_f32(-1e30f);
    for (int i = threadIdx.x; i < BDIM; i += 256) {
      minpos_e[i] = init_min;
      maxneg_e[i] = init_max;
    }
  }
  const int row  = blockIdx.x * 4 + (threadIdx.x >> 6);
  const int lane = threadIdx.x & 63;
  const float4* xr = reinterpret_cast<const float4*>(x + (size_t)row * DDIM);
  float4 v0 = xr[lane];
  float4 v1 = xr[lane + 64];
  float ss = v0.x*v0.x + v0.y*v0.y + v0.z*v0.z + v0.w*v0.w
           + v1.x*v1.x + v1.y*v1.y + v1.z*v1.z + v1.w*v1.w;
#pragma unroll
  for (int off = 32; off >= 1; off >>= 1) ss += __shfl_xor(ss, off);
  const float inv = 1.0f / fmaxf(sqrtf(ss), 1e-12f);

  ushort4 p0, p1;
  p0.x = f2bf(v0.x * inv); p0.y = f2bf(v0.y * inv);
  p0.z = f2bf(v0.z * inv); p0.w = f2bf(v0.w * inv);
  p1.x = f2bf(v1.x * inv); p1.y = f2bf(v1.y * inv);
  p1.z = f2bf(v1.z * inv); p1.w = f2bf(v1.w * inv);
  ushort4* er = reinterpret_cast<ushort4*>(e + (size_t)row * DDIM);
  er[lane]      = p0;
  er[lane + 64] = p1;
}

// --- kernel 2: 256^2 GEMM, 3-buffer ring, counted vmcnt (never 0 mid-loop) --
// Per buffer: A [256 rows][32 k] bf16 (16 KB) + B same (16 KB) = 32 KB; x3.
// compute(kt) from buf[kt%3] while stage(kt+2) -> buf[(kt+2)%3]: writer never
// touches a buffer being read. Boundary: vmcnt(4) retires stage(kt+1) only;
// raw s_barrier ("memory" clobber, no waitcnt drain). No other VMEM in loop.
// Granule-permute swizzle (R8-verified) on BOTH sides (rule #21).
#define STAGE(bi, kt)                                                          \
  do {                                                                         \
    _Pragma("unroll")                                                          \
    for (int q = 0; q < 2; ++q) {  /* A rows 0..255 */                         \
      const int off = q * 8192 + tid * 16;                                     \
      const int row = off >> 6;                                                \
      const int gg  = (off >> 4) & 3;                                          \
      const char* src = (const char*)e + (size_t)(Ibase + row) * (DDIM * 2) +  \
                        (kt) * 64 + ((gg ^ ((row >> 1) & 3)) << 4);            \
      __builtin_amdgcn_global_load_lds(                                        \
          (const __attribute__((address_space(1))) void*)src,                  \
          (__attribute__((address_space(3))) void*)(&Blds[bi][off]),           \
          16, 0, 0);                                                           \
    }                                                                          \
    _Pragma("unroll")                                                          \
    for (int q = 0; q < 2; ++q) {  /* B rows 0..255 */                         \
      const int off = q * 8192 + tid * 16;                                     \
      const int row = off >> 6;                                                \
      const int gg  = (off >> 4) & 3;                                          \
      const char* src = (const char*)e + (size_t)(Jbase + row) * (DDIM * 2) +  \
                        (kt) * 64 + ((gg ^ ((row >> 1) & 3)) << 4);            \
      __builtin_amdgcn_global_load_lds(                                        \
          (const __attribute__((address_space(1))) void*)src,                  \
          (__attribute__((address_space(3))) void*)(&Blds[bi][16384 + off]),   \
          16, 0, 0);                                                           \
    }                                                                          \
  } while (0)

__global__ __launch_bounds__(512, 1) void gemm_reduce_kernel(
    const ushort_t* __restrict__ e, const int* __restrict__ labels,
    unsigned int* __restrict__ minpos_e, unsigned int* __restrict__ maxneg_e) {
  __shared__ __align__(16) char Blds[3][32768];
  __shared__ int Llab[512];

  const int tid  = threadIdx.x;
  const int wave = tid >> 6;      // 0..7
  const int lane = tid & 63;
  const int l15  = lane & 15;
  const int g    = lane >> 4;     // 0..3
  const int wr   = wave >> 2;     // 0..1: 128-row half
  const int wc   = wave & 3;      // 0..3: 64-col quarter

  // bijective XCD swizzle: 256 blocks = 8 XCDs x 32; J fastest within XCD
  const int bid  = blockIdx.x;
  const int sbid = (bid & 7) * (GRIDX / 8) + (bid >> 3);
  const int Ibase = (sbid >> 4) * BT;
  const int Jbase = (sbid & 15) * BT;

  f32x4 acc[8][4];
#pragma unroll
  for (int m = 0; m < 8; ++m)
#pragma unroll
    for (int n = 0; n < 4; ++n) acc[m][n] = (f32x4){0.f, 0.f, 0.f, 0.f};

  STAGE(0, 0);
  STAGE(1, 1);
  WAITV4();   // stage(0) retired; stage(1) may remain in flight
  BAR();

#pragma unroll
  for (int kt = 0; kt < NKT; ++kt) {
    if (kt + 2 < NKT) STAGE((kt + 2) % 3, kt + 2);

    const char* Ab = Blds[kt % 3];
    const char* Bb = Ab + 16384;
    bf16x8 a[8], b[4];
#pragma unroll
    for (int m = 0; m < 8; ++m) {
      const int row = wr * 128 + m * 16 + l15;
      a[m] = *reinterpret_cast<const bf16x8*>(
          Ab + row * 64 + ((g ^ ((row >> 1) & 3)) << 4));
    }
#pragma unroll
    for (int n = 0; n < 4; ++n) {
      const int row = wc * 64 + n * 16 + l15;
      b[n] = *reinterpret_cast<const bf16x8*>(
          Bb + row * 64 + ((g ^ ((row >> 1) & 3)) << 4));
    }
    __builtin_amdgcn_s_setprio(1);
#pragma unroll
    for (int m = 0; m < 8; ++m)
#pragma unroll
      for (int n = 0; n < 4; ++n)
        acc[m][n] = __builtin_amdgcn_mfma_f32_16x16x32_bf16(a[m], b[n],
                                                            acc[m][n], 0, 0, 0);
    __builtin_amdgcn_s_setprio(0);

    if (kt + 2 < NKT) { WAITV4(); } else { WAITV0(); }  // retire stage(kt+1)
    BAR();  // all waves done reading buf[kt%3]; staging visible block-wide
  }

  // ---- labels to LDS (safe now: loop's vmcnt fully drained) --------------
  if (tid < 256) Llab[tid] = labels[Ibase + tid];
  else           Llab[tid] = labels[Jbase + tid - 256];
  __syncthreads();

  // ---- fused epilogue: per-COLUMN masked min/max (S symmetric) ----------
  // C/D 16x16 layout: col = l15, row = g*4 + r. A lane's 32 values (m,r) all
  // sit in its 4 columns (n, l15) -> in-lane reduce + 2 shuffles across g.
  float cmp[4], cmx[4];
  int lj[4], gj[4];
#pragma unroll
  for (int n = 0; n < 4; ++n) {
    cmp[n] = 1e30f; cmx[n] = -1e30f;
    gj[n]  = Jbase + wc * 64 + n * 16 + l15;
    lj[n]  = Llab[256 + wc * 64 + n * 16 + l15];
  }
#pragma unroll
  for (int m = 0; m < 8; ++m) {
#pragma unroll
    for (int r = 0; r < 4; ++r) {
      const int rloc = wr * 128 + m * 16 + g * 4 + r;
      const int li   = Llab[rloc];
      const int gi   = Ibase + rloc;
#pragma unroll
      for (int n = 0; n < 4; ++n) {
        const float v = acc[m][n][r];
        if (li == lj[n]) {
          if (gi != gj[n]) cmp[n] = fminf(cmp[n], v);
        } else {
          cmx[n] = fmaxf(cmx[n], v);
        }
      }
    }
  }
  // reduce across the 4 lanes (g = 0..3) sharing each column
#pragma unroll
  for (int off = 16; off <= 32; off <<= 1) {
#pragma unroll
    for (int n = 0; n < 4; ++n) {
      cmp[n] = fminf(cmp[n], __shfl_xor(cmp[n], off));
      cmx[n] = fmaxf(cmx[n], __shfl_xor(cmx[n], off));
    }
  }
  if (g == 0) {
#pragma unroll
    for (int n = 0; n < 4; ++n) {
      if (cmp[n] < 1e29f)  atomicMin(&minpos_e[gj[n]], enc_f32(cmp[n]));
      if (cmx[n] > -1e29f) atomicMax(&maxneg_e[gj[n]], enc_f32(cmx[n]));
    }
  }
}

// ---------------- kernel 3: combine -> scalar loss ----------------
__global__ __launch_bounds__(1024) void finalize_kernel(
    const unsigned int* __restrict__ minpos_e, const unsigned int* __restrict__ maxneg_e,
    float* __restrict__ out) {
  const int tid = threadIdx.x;
  float sum = 0.f;
  int cnt = 0;
  for (int row = tid; row < BDIM; row += 1024) {
    const float mp = dec_f32(minpos_e[row]);
    const float mn = dec_f32(maxneg_e[row]);
    if (mp < 1e29f && mn > -1e29f) {
      // hp - hn + margin = (1-mp) - (1-mn) + 0.2 = mn - mp + 0.2
      sum += fmaxf(0.f, mn - mp + 0.2f);
      cnt += 1;
    }
  }
#pragma unroll
  for (int off = 32; off >= 1; off >>= 1) {
    sum += __shfl_xor(sum, off);
    cnt += __shfl_xor(cnt, off);
  }
  __shared__ float wsum[16];
  __shared__ int   wcnt[16];
  const int wv = tid >> 6, ln = tid & 63;
  if (ln == 0) { wsum[wv] = sum; wcnt[wv] = cnt; }
  __syncthreads();
  if (tid == 0) {
    float S = 0.f; int C = 0;
    for (int w = 0; w < 16; ++w) { S += wsum[w]; C += wcnt[w]; }
    out[0] = S / (float)(C > 0 ? C : 1);
  }
}

extern "C" void kernel_launch(void* const* d_in, const int* in_sizes, int n_in,
                              void* d_out, int out_size, void* d_ws, size_t ws_size,
                              hipStream_t stream) {
  const float* x      = (const float*)d_in[0];
  const int*   labels = (const int*)d_in[1];
  float* out = (float*)d_out;

  char* ws = (char*)d_ws;
  ushort_t* e            = (ushort_t*)ws;                            // 4 MB bf16 E
  unsigned int* minpos_e = (unsigned int*)(ws + (size_t)BDIM * DDIM * 2);
  unsigned int* maxneg_e = minpos_e + BDIM;

  norm_kernel<<<BDIM / 4, 256, 0, stream>>>(x, e, minpos_e, maxneg_e);
  gemm_reduce_kernel<<<GRIDX, 512, 0, stream>>>(e, labels, minpos_e, maxneg_e);
  finalize_kernel<<<1, 1024, 0, stream>>>(minpos_e, maxneg_e, out);
}

// Round 16
// 32.434 us; speedup vs baseline: 1.0680x; 1.0680x over previous
//
#include <hip/hip_runtime.h>
#include <hip/hip_bf16.h>

#define BDIM 4096
#define DDIM 512
#define BT 256                    // block tile (rows == cols)
#define BK 64                     // K per tile-step
#define NKT (DDIM / BK)           // 8 K tiles
#define NPAN (BDIM / BT)          // 16 panels
#define GRIDX (NPAN * NPAN)       // 256 blocks = 1 per CU

typedef __bf16 bf16x8 __attribute__((ext_vector_type(8)));
typedef float f32x4 __attribute__((ext_vector_type(4)));
typedef unsigned short ushort_t;

__device__ inline ushort_t f2bf(float f) {
  __hip_bfloat16 h = __float2bfloat16(f);
  return *reinterpret_cast<ushort_t*>(&h);
}

// order-preserving float <-> uint mapping (monotonic) for atomic min/max
__device__ inline unsigned int enc_f32(float x) {
  unsigned int u = __float_as_uint(x);
  return (u & 0x80000000u) ? ~u : (u | 0x80000000u);
}
__device__ inline float dec_f32(unsigned int e) {
  unsigned int u = (e & 0x80000000u) ? (e ^ 0x80000000u) : ~e;
  return __uint_as_float(u);
}

// ---------------- kernel 1: L2-normalize rows, emit bf16; init atomics -----
__global__ __launch_bounds__(256) void norm_kernel(const float* __restrict__ x,
                                                   ushort_t* __restrict__ e,
                                                   unsigned int* __restrict__ minpos_e,
                                                   unsigned int* __restrict__ maxneg_e) {
  if (blockIdx.x == 0) {  // init atomic arrays (stream order: before gemm)
    const unsigned int init_min = enc_f32(1e30f);
    const unsigned int init_max = enc_f32(-1e30f);
    for (int i = threadIdx.x; i < BDIM; i += 256) {
      minpos_e[i] = init_min;
      maxneg_e[i] = init_max;
    }
  }
  const int row  = blockIdx.x * 4 + (threadIdx.x >> 6);
  const int lane = threadIdx.x & 63;
  const float4* xr = reinterpret_cast<const float4*>(x + (size_t)row * DDIM);
  float4 v0 = xr[lane];
  float4 v1 = xr[lane + 64];
  float ss = v0.x*v0.x + v0.y*v0.y + v0.z*v0.z + v0.w*v0.w
           + v1.x*v1.x + v1.y*v1.y + v1.z*v1.z + v1.w*v1.w;
#pragma unroll
  for (int off = 32; off >= 1; off >>= 1) ss += __shfl_xor(ss, off);
  const float inv = 1.0f / fmaxf(sqrtf(ss), 1e-12f);

  ushort4 p0, p1;
  p0.x = f2bf(v0.x * inv); p0.y = f2bf(v0.y * inv);
  p0.z = f2bf(v0.z * inv); p0.w = f2bf(v0.w * inv);
  p1.x = f2bf(v1.x * inv); p1.y = f2bf(v1.y * inv);
  p1.z = f2bf(v1.z * inv); p1.w = f2bf(v1.w * inv);
  ushort4* er = reinterpret_cast<ushort4*>(e + (size_t)row * DDIM);
  er[lane]      = p0;
  er[lane + 64] = p1;
}

// --- kernel 2: 256^2 GEMM, 16 waves of 64x64 (4 waves/SIMD), fused reduce ---
// LDS per buffer: A [256 rows][64 k] bf16 (32 KB) + B same (32 KB); dbuf 128KB.
// T2 XOR swizzle (byte ^= (row&7)<<4, rows are 128 B) on BOTH sides (rule #21).
// acc 4x4 = 64 VGPR -> ~110 total -> 4 waves/SIMD for latency hiding.
#define STAGE(buf, kt)                                                         \
  do {                                                                         \
    _Pragma("unroll")                                                          \
    for (int q = 0; q < 4; ++q) {                                              \
      const int off  = q * 16384 + tid * 16;  /* 0..65535 */                   \
      const int loff = off & 32767;                                            \
      const int row  = loff >> 7;                                              \
      const int kb   = loff & 127;                                             \
      const int pan  = (q < 2) ? Ibase : Jbase;                                \
      const char* src = (const char*)e + (size_t)(pan + row) * (DDIM * 2) +    \
                        (kt) * 128 + (kb ^ ((row & 7) << 4));                  \
      __builtin_amdgcn_global_load_lds(                                        \
          (const __attribute__((address_space(1))) void*)src,                  \
          (__attribute__((address_space(3))) void*)(&Blds[buf][off]),          \
          16, 0, 0);                                                           \
    }                                                                          \
  } while (0)

__global__ __launch_bounds__(1024, 1) void gemm_reduce_kernel(
    const ushort_t* __restrict__ e, const int* __restrict__ labels,
    unsigned int* __restrict__ minpos_e, unsigned int* __restrict__ maxneg_e) {
  __shared__ __align__(16) char Blds[2][65536];
  __shared__ int Llab[512];

  const int tid  = threadIdx.x;
  const int wave = tid >> 6;      // 0..15
  const int lane = tid & 63;
  const int l15  = lane & 15;
  const int g    = lane >> 4;     // 0..3
  const int wr   = wave >> 2;     // 0..3: 64-row band
  const int wc   = wave & 3;      // 0..3: 64-col band

  // bijective XCD swizzle: 256 blocks = 8 XCDs x 32; J fastest within XCD
  const int bid  = blockIdx.x;
  const int sbid = (bid & 7) * (GRIDX / 8) + (bid >> 3);
  const int Ibase = (sbid >> 4) * BT;
  const int Jbase = (sbid & 15) * BT;

  // stage labels for this block's rows (I) and cols (J)
  if (tid < 256)      Llab[tid] = labels[Ibase + tid];
  else if (tid < 512) Llab[tid] = labels[Jbase + tid - 256];

  f32x4 acc[4][4];
#pragma unroll
  for (int m = 0; m < 4; ++m)
#pragma unroll
    for (int n = 0; n < 4; ++n) acc[m][n] = (f32x4){0.f, 0.f, 0.f, 0.f};

  STAGE(0, 0);
  __syncthreads();  // vmcnt drained at barrier: buf0 + labels ready

  for (int kt = 0; kt < NKT; ++kt) {
    if (kt + 1 < NKT) STAGE((kt + 1) & 1, kt + 1);  // async prefetch

    const char* Ab = Blds[kt & 1];
    const char* Bb = Blds[kt & 1] + 32768;
#pragma unroll
    for (int kk = 0; kk < 2; ++kk) {
      bf16x8 a[4], b[4];
#pragma unroll
      for (int m = 0; m < 4; ++m) {
        const int row = wr * 64 + m * 16 + l15;
        a[m] = *reinterpret_cast<const bf16x8*>(
            Ab + row * 128 + ((kk * 64 + g * 16) ^ ((row & 7) << 4)));
      }
#pragma unroll
      for (int n = 0; n < 4; ++n) {
        const int row = wc * 64 + n * 16 + l15;
        b[n] = *reinterpret_cast<const bf16x8*>(
            Bb + row * 128 + ((kk * 64 + g * 16) ^ ((row & 7) << 4)));
      }
#pragma unroll
      for (int m = 0; m < 4; ++m)
#pragma unroll
        for (int n = 0; n < 4; ++n)
          acc[m][n] = __builtin_amdgcn_mfma_f32_16x16x32_bf16(a[m], b[n],
                                                              acc[m][n], 0, 0, 0);
    }
    __syncthreads();  // staged(kt+1) complete + cur buffer release
  }

  // ---- fused epilogue: per-COLUMN masked min/max (S symmetric) ----------
  // C/D 16x16 layout: col = l15, row = g*4 + r. A lane's 16 values (m,r) all
  // sit in its 4 columns (n, l15) -> in-lane reduce + 2 shuffles across g.
  // The 4 waves (wr=0..3) sharing a column emit separate atomics (idempotent).
  float cmp[4], cmx[4];
  int lj[4], gj[4];
#pragma unroll
  for (int n = 0; n < 4; ++n) {
    cmp[n] = 1e30f; cmx[n] = -1e30f;
    gj[n]  = Jbase + wc * 64 + n * 16 + l15;
    lj[n]  = Llab[256 + wc * 64 + n * 16 + l15];
  }
#pragma unroll
  for (int m = 0; m < 4; ++m) {
#pragma unroll
    for (int r = 0; r < 4; ++r) {
      const int rloc = wr * 64 + m * 16 + g * 4 + r;
      const int li   = Llab[rloc];
      const int gi   = Ibase + rloc;
#pragma unroll
      for (int n = 0; n < 4; ++n) {
        const float v = acc[m][n][r];
        if (li == lj[n]) {
          if (gi != gj[n]) cmp[n] = fminf(cmp[n], v);
        } else {
          cmx[n] = fmaxf(cmx[n], v);
        }
      }
    }
  }
  // reduce across the 4 lanes (g = 0..3) sharing each column
#pragma unroll
  for (int off = 16; off <= 32; off <<= 1) {
#pragma unroll
    for (int n = 0; n < 4; ++n) {
      cmp[n] = fminf(cmp[n], __shfl_xor(cmp[n], off));
      cmx[n] = fmaxf(cmx[n], __shfl_xor(cmx[n], off));
    }
  }
  if (g == 0) {
#pragma unroll
    for (int n = 0; n < 4; ++n) {
      if (cmp[n] < 1e29f)  atomicMin(&minpos_e[gj[n]], enc_f32(cmp[n]));
      if (cmx[n] > -1e29f) atomicMax(&maxneg_e[gj[n]], enc_f32(cmx[n]));
    }
  }
}

// ---------------- kernel 3: combine -> scalar loss ----------------
__global__ __launch_bounds__(1024) void finalize_kernel(
    const unsigned int* __restrict__ minpos_e, const unsigned int* __restrict__ maxneg_e,
    float* __restrict__ out) {
  const int tid = threadIdx.x;
  float sum = 0.f;
  int cnt = 0;
  for (int row = tid; row < BDIM; row += 1024) {
    const float mp = dec_f32(minpos_e[row]);
    const float mn = dec_f32(maxneg_e[row]);
    if (mp < 1e29f && mn > -1e29f) {
      // hp - hn + margin = (1-mp) - (1-mn) + 0.2 = mn - mp + 0.2
      sum += fmaxf(0.f, mn - mp + 0.2f);
      cnt += 1;
    }
  }
#pragma unroll
  for (int off = 32; off >= 1; off >>= 1) {
    sum += __shfl_xor(sum, off);
    cnt += __shfl_xor(cnt, off);
  }
  __shared__ float wsum[16];
  __shared__ int   wcnt[16];
  const int wv = tid >> 6, ln = tid & 63;
  if (ln == 0) { wsum[wv] = sum; wcnt[wv] = cnt; }
  __syncthreads();
  if (tid == 0) {
    float S = 0.f; int C = 0;
    for (int w = 0; w < 16; ++w) { S += wsum[w]; C += wcnt[w]; }
    out[0] = S / (float)(C > 0 ? C : 1);
  }
}

extern "C" void kernel_launch(void* const* d_in, const int* in_sizes, int n_in,
                              void* d_out, int out_size, void* d_ws, size_t ws_size,
                              hipStream_t stream) {
  const float* x      = (const float*)d_in[0];
  const int*   labels = (const int*)d_in[1];
  float* out = (float*)d_out;

  char* ws = (char*)d_ws;
  ushort_t* e            = (ushort_t*)ws;                            // 4 MB bf16 E
  unsigned int* minpos_e = (unsigned int*)(ws + (size_t)BDIM * DDIM * 2);
  unsigned int* maxneg_e = minpos_e + BDIM;

  norm_kernel<<<BDIM / 4, 256, 0, stream>>>(x, e, minpos_e, maxneg_e);
  gemm_reduce_kernel<<<GRIDX, 1024, 0, stream>>>(e, labels, minpos_e, maxneg_e);
  finalize_kernel<<<1, 1024, 0, stream>>>(minpos_e, maxneg_e, out);
}